// Round 2
// baseline (168.508 us; speedup 1.0000x reference)
//
#include <hip/hip_runtime.h>
#include <stdint.h>

#define OUT_F   4096
#define IN_F    11008
#define BATCH   64
#define NSUP    43                  // super-blocks per row
#define SB_ROW  344                 // sub-blocks per row
#define IPR     5504                // int32 elements per weight row
#define NKS     12                  // K-splits -> 64 x 12 = 768 blocks = 3/CU exactly
#define XP_BYTES   (4 * 344 * 64 * 16)              // 1,409,024 B
#define PART_ELEMS ((size_t)NKS * BATCH * OUT_F)
#define WS_FULL    (XP_BYTES + PART_ELEMS * 4)

typedef __attribute__((ext_vector_type(8))) short  short8;
typedef __attribute__((ext_vector_type(4))) float  floatx4;
typedef __attribute__((ext_vector_type(4))) int    intx4;

template<int N> struct IC { static constexpr int value = N; };

__device__ __forceinline__ unsigned pack_bf16(float f0, float f1) {
    return __builtin_amdgcn_perm(__float_as_uint(f1), __float_as_uint(f0), 0x07060302u);
}

// global -> LDS direct copy, 16B per lane, dest = wave-uniform base + lane*16
__device__ __forceinline__ void glds16(const void* g, void* s) {
    __builtin_amdgcn_global_load_lds(
        (const __attribute__((address_space(1))) uint32_t*)g,
        (__attribute__((address_space(3))) uint32_t*)s,
        16, 0, 0);
}

__device__ __forceinline__ void wait_vm0(void) {
    asm volatile("s_waitcnt vmcnt(0)" ::: "memory");
    __builtin_amdgcn_sched_barrier(0);      // rule #18: fence against hoisting
}

// ---- pre-pack x into MFMA A-fragment order: xp[(mt*344 + ksb)*64 + l] ----
__global__ __launch_bounds__(256) void xprep_kernel(const float* __restrict__ x,
                                                    intx4* __restrict__ xp) {
    const int ksb = blockIdx.x;            // 0..343
    const int mt  = threadIdx.x >> 6;
    const int l   = threadIdx.x & 63;
    const int lo  = l & 15, hi = l >> 4;
    const float* src = x + (mt * 16 + lo) * IN_F + ksb * 32 + hi * 8;
    floatx4 a0 = *(const floatx4*)src;
    floatx4 a1 = *(const floatx4*)(src + 4);
    intx4 r;
    r.x = pack_bf16(a0.x, a0.y);
    r.y = pack_bf16(a0.z, a0.w);
    r.z = pack_bf16(a1.x, a1.y);
    r.w = pack_bf16(a1.z, a1.w);
    xp[(mt * 344 + ksb) * 64 + l] = r;
}

__global__ __launch_bounds__(256) void init_out_kernel(const float* __restrict__ bias,
                                                       float* __restrict__ out) {
    int i = blockIdx.x * 256 + threadIdx.x;
    out[i] = bias[i & (OUT_F - 1)];
}

__global__ __launch_bounds__(256) void reduce_kernel(const float* __restrict__ part,
                                                     const float* __restrict__ bias,
                                                     float* __restrict__ out) {
    const int i = blockIdx.x * 256 + threadIdx.x;
    float s = bias[i & (OUT_F - 1)];
    #pragma unroll
    for (int k = 0; k < NKS; ++k) s += part[(size_t)k * (BATCH * OUT_F) + i];
    out[i] = s;
}

// block = 64 out-features x 64 batch rows.
// Software-pipelined over super-blocks:
//   - weights/scales for super s+1 prefetched into regs DURING compute of s
//   - x fragments staged via global_load_lds (no VGPR round-trip, no ds_write)
//   - raw s_barrier (no compiler vmcnt(0) drain) keeps the HBM weight stream
//     in flight across barriers; the only vmcnt(0) sits after the L2-hot glds.
template<bool USE_PART>
__global__ __launch_bounds__(256, 3) void qlin_main(
    const intx4* __restrict__ xp,
    const int*   __restrict__ packed,
    const float* __restrict__ dd,
    const float* __restrict__ dmn_g,
    const int*   __restrict__ scales,
    const int*   __restrict__ mins,
    float*       __restrict__ part,
    float*       __restrict__ out)
{
    __shared__ intx4 xfs[2048];     // 32KB  [mt*512 + st*64 + l]

    const int nb  = blockIdx.x & 63;
    const int ks  = blockIdx.x >> 6;          // 0..11
    const int tid = threadIdx.x;
    const int w   = tid >> 6;
    const int l   = tid & 63;
    const int lo  = l & 15, hi = l >> 4;
    const int wq  = tid & 192;                // w*64: wave-uniform LDS slice

    const int o    = nb * 64 + w * 16 + lo;   // lane's out-feature (== row in block)
    const int sup0 = ks < 7 ? 4 * ks : 28 + 3 * (ks - 7);
    const int nsup = ks < 7 ? 4 : 3;

    floatx4 acc[4];
    #pragma unroll
    for (int mt = 0; mt < 4; ++mt) acc[mt] = (floatx4)0.0f;

    const int*   bp0 = packed + o * IPR + sup0 * 128 + hi * 4;
    const int*   scp = scales + o * SB_ROW + sup0 * 8;
    const int*   mnp = mins   + o * SB_ROW + sup0 * 8;
    const float* dp  = dd     + o * NSUP + sup0;
    const float* dmp = dmn_g  + o * NSUP + sup0;

    // issue the 8 global_load_lds for one super's x tile (1KB per wave-instr)
    auto stage_x = [&](int sup_abs) {
        #pragma unroll
        for (int i = 0; i < 8; ++i) {
            const int mt = i >> 1;
            const intx4* src = xp + sup_abs * 512 + mt * 22016 + (i & 1) * 256 + tid;
            glds16((const void*)src, (void*)&xfs[i * 256 + wq]);
        }
    };

    // prefetch one super's unique weights + dequant scalars into regs
    auto load_wblk = [&](int s, intx4 br[8], intx4& s0v, intx4& s1v,
                         intx4& m0v, intx4& m1v, float& dv, float& dmv) {
        #pragma unroll
        for (int st = 0; st < 8; ++st)
            br[st] = __builtin_nontemporal_load((const intx4*)(bp0 + s * 128 + st * 16));
        s0v = *(const intx4*)(scp + s * 8);
        s1v = *(const intx4*)(scp + s * 8 + 4);
        m0v = *(const intx4*)(mnp + s * 8);
        m1v = *(const intx4*)(mnp + s * 8 + 4);
        dv  = dp[s];
        dmv = dmp[s];
    };

    // 8 K-steps: ds_read fragments + dequant + MFMA (no vmem waits inside)
    auto compute_sup = [&](const intx4 br[8], intx4 s0v, intx4 s1v,
                           intx4 m0v, intx4 m1v, float dv, float dmv) {
        const float A945 = dv * (1.0f / 945.0f);
        const float A63  = dv * (1.0f / 63.0f);
        #pragma unroll
        for (int st = 0; st < 8; ++st) {
            const int scv = (st < 4) ? s0v[st & 3] : s1v[st & 3];
            const int mnv = (st < 4) ? m0v[st & 3] : m1v[st & 3];
            const float A = A945 * (float)scv;
            const float B = fmaf(A63, (float)mnv, dmv);
            const int v0 = br[st].x, v1 = br[st].y, v2 = br[st].z, v3 = br[st].w;
            union { intx4 i; short8 s8; } uw;
            uw.i.x = pack_bf16(fmaf((float)(v0 & 15), A, B), fmaf((float)(v0 >> 4), A, B));
            uw.i.y = pack_bf16(fmaf((float)(v1 & 15), A, B), fmaf((float)(v1 >> 4), A, B));
            uw.i.z = pack_bf16(fmaf((float)(v2 & 15), A, B), fmaf((float)(v2 >> 4), A, B));
            uw.i.w = pack_bf16(fmaf((float)(v3 & 15), A, B), fmaf((float)(v3 >> 4), A, B));

            union { intx4 i; short8 s8; } u0, u1, u2, u3;
            u0.i = xfs[0 * 512 + st * 64 + l];
            u1.i = xfs[1 * 512 + st * 64 + l];
            u2.i = xfs[2 * 512 + st * 64 + l];
            u3.i = xfs[3 * 512 + st * 64 + l];
            acc[0] = __builtin_amdgcn_mfma_f32_16x16x32_bf16(u0.s8, uw.s8, acc[0], 0, 0, 0);
            acc[1] = __builtin_amdgcn_mfma_f32_16x16x32_bf16(u1.s8, uw.s8, acc[1], 0, 0, 0);
            acc[2] = __builtin_amdgcn_mfma_f32_16x16x32_bf16(u2.s8, uw.s8, acc[2], 0, 0, 0);
            acc[3] = __builtin_amdgcn_mfma_f32_16x16x32_bf16(u3.s8, uw.s8, acc[3], 0, 0, 0);
        }
    };

    auto run = [&](auto nsc) {
        constexpr int NS = decltype(nsc)::value;
        intx4 br[8]; intx4 s0v, s1v, m0v, m1v; float dv, dmv;

        // prologue: issue HBM weight loads first, then L2-hot x staging
        load_wblk(0, br, s0v, s1v, m0v, m1v, dv, dmv);
        stage_x(sup0);
        wait_vm0();
        __builtin_amdgcn_s_barrier();

        #pragma unroll
        for (int s = 0; s < NS; ++s) {
            intx4 brN[8]; intx4 s0N, s1N, m0N, m1N; float dvN, dmvN;
            if (s + 1 < NS)
                load_wblk(s + 1, brN, s0N, s1N, m0N, m1N, dvN, dmvN);   // flies behind compute

            compute_sup(br, s0v, s1v, m0v, m1v, dv, dmv);

            if (s + 1 < NS) {
                __builtin_amdgcn_s_barrier();                           // all waves done reading xfs
                stage_x(sup0 + s + 1);                                  // L2-hot, ~300cy
                wait_vm0();                                             // glds done (brN long arrived)
                __builtin_amdgcn_s_barrier();                           // xfs visible to all waves
                #pragma unroll
                for (int i2 = 0; i2 < 8; ++i2) br[i2] = brN[i2];        // SSA renames under unroll
                s0v = s0N; s1v = s1N; m0v = m0N; m1v = m1N; dv = dvN; dmv = dmvN;
            }
        }
    };
    if (nsup == 4) run(IC<4>{});
    else           run(IC<3>{});

    // ---- epilogue: D col = lane&15 = n (out-feature o), row = hi*4+rr = m ----
    if (USE_PART) {
        float* pbase = part + (size_t)ks * (BATCH * OUT_F) + o;
        #pragma unroll
        for (int mt = 0; mt < 4; ++mt) {
            #pragma unroll
            for (int rr = 0; rr < 4; ++rr)
                pbase[(mt * 16 + hi * 4 + rr) * OUT_F] = acc[mt][rr];
        }
    } else {
        #pragma unroll
        for (int mt = 0; mt < 4; ++mt) {
            #pragma unroll
            for (int rr = 0; rr < 4; ++rr)
                atomicAdd(out + (mt * 16 + hi * 4 + rr) * OUT_F + o, acc[mt][rr]);
        }
    }
}

extern "C" void kernel_launch(void* const* d_in, const int* in_sizes, int n_in,
                              void* d_out, int out_size, void* d_ws, size_t ws_size,
                              hipStream_t stream) {
    (void)in_sizes; (void)n_in; (void)out_size;
    const float* x      = (const float*)d_in[0];
    const int*   packed = (const int*)d_in[1];
    const float* d      = (const float*)d_in[2];
    const float* dmin   = (const float*)d_in[3];
    const int*   scales = (const int*)d_in[4];
    const int*   mins   = (const int*)d_in[5];
    const float* bias   = (const float*)d_in[6];
    float* out = (float*)d_out;

    const bool has_part = ws_size >= (size_t)WS_FULL;
    intx4* xp   = (intx4*)d_ws;
    float* part = (float*)((char*)d_ws + XP_BYTES);

    xprep_kernel<<<344, 256, 0, stream>>>(x, xp);

    if (has_part) {
        qlin_main<true><<<64 * NKS, 256, 0, stream>>>(
            xp, packed, d, dmin, scales, mins, part, out);
        reduce_kernel<<<(BATCH * OUT_F) / 256, 256, 0, stream>>>(part, bias, out);
    } else {
        init_out_kernel<<<(BATCH * OUT_F) / 256, 256, 0, stream>>>(bias, out);
        qlin_main<false><<<64 * NKS, 256, 0, stream>>>(
            xp, packed, d, dmin, scales, mins, part, out);
    }
}